// Round 3
// baseline (37.144 us; speedup 1.0000x reference)
//
#include <hip/hip_runtime.h>
#include <hip/hip_bf16.h>

#define HOURS 24
#define MM 128
#define EE 128

typedef short bf16x8 __attribute__((ext_vector_type(8)));
typedef float f32x4 __attribute__((ext_vector_type(4)));

__device__ __forceinline__ unsigned short f2bfu(float f) {
    __hip_bfloat16 h = __float2bfloat16(f);
    return __builtin_bit_cast(unsigned short, h);
}
__device__ __forceinline__ unsigned int pack2(float a, float b) {
    return (unsigned int)f2bfu(a) | ((unsigned int)f2bfu(b) << 16);
}
// swizzled short-index of 16B unit `unit` in row `row` of a [*][128] bf16 tile
__device__ __forceinline__ int swz8(int row, int unit) {
    return row * 128 + (((unit ^ (row & 7)) & 15) << 3);
}
// load 8 consecutive f32 from global, convert to bf16x8 fragment
__device__ __forceinline__ bf16x8 load_w_frag(const float* base) {
    float4 x = *(const float4*)base;
    float4 y = *(const float4*)(base + 4);
    union { unsigned int u[4]; bf16x8 v; } r;
    r.u[0] = pack2(x.x, x.y); r.u[1] = pack2(x.z, x.w);
    r.u[2] = pack2(y.x, y.y); r.u[3] = pack2(y.z, y.w);
    return r.v;
}

#define MFMA(a, b, c) __builtin_amdgcn_mfma_f32_16x16x32_bf16(a, b, c, 0, 0, 0)

// One block = (batch b, half). 1024 threads = 16 waves.
// Phases: 1) gather J + coefs  2) K/VT/Q GEMMs into LDS  3a) QK^T -> S
// 3b) softmax -> P, tms/bsv  3c) PV -> sa (waves 0-7) || stage cand+mat2 (waves 8-15)
// 4) G = cand . sa^T, epilogue, atomicAdd to out (m-split across the 2 half-blocks)
__global__ __launch_bounds__(1024) void k_fused(
    const int* __restrict__ full_seq, const int* __restrict__ time_seq,
    const int* __restrict__ user, const int* __restrict__ posneg,
    const int* __restrict__ traj_len,
    const float* __restrict__ mat1, const float* __restrict__ mat2,
    const float* __restrict__ vecg,
    const float* __restrict__ emb_t, const float* __restrict__ emb_u,
    const float* __restrict__ emb_loc,
    const float* __restrict__ esl, const float* __restrict__ esu,
    const float* __restrict__ etl, const float* __restrict__ etu,
    const float* __restrict__ Wq, const float* __restrict__ Wk,
    const float* __restrict__ Wv,
    float* __restrict__ outp)
{
    // A: J(bf16 32KB) -> S(f32 [4][16][132]) -> cand(bf16 32KB)   33792 B
    __shared__ alignas(16) short A_s[16896];
    // B: K(bf16 32KB) -> mat2 (f32 [64][136])                      34816 B
    __shared__ alignas(16) short B_s[17408];
    // C: VT (bf16, rows e over m)                                  32768 B
    __shared__ alignas(16) short C_s[16384];
    // D: Q (64x128 bf16) -> P (4 chunks x 16x128 bf16)             16384 B
    __shared__ alignas(16) short D_s[8192];
    // E: sa (64x128 bf16)                                          16384 B
    __shared__ alignas(16) short E_s[8192];
    __shared__ float tms[64], bsv[64], coef[8];

    int bid = blockIdx.x;
    int b = bid >> 1, half = bid & 1;
    int i0base = half * 64;
    int tid = threadIdx.x;
    int w = tid >> 6, l = tid & 63;
    int lr = l & 15, lg = l >> 4;
    int tl = traj_len[b];

    // ---------------- phase 1: coefs (waves 8-15) + gather J ----------------
    if (w >= 8) {
        int c = w - 8;
        const float* t = (c < 2) ? esl : (c < 4) ? esu : (c < 6) ? etl : etu;
        int row = c & 1;
        float v = t[row * 128 + l] + t[row * 128 + 64 + l];
#pragma unroll
        for (int off = 32; off >= 1; off >>= 1) v += __shfl_xor(v, off, 64);
        if (l == 0) coef[c] = v;
    }
    {
        int uid = user[b];
        const float4* Eu4 = (const float4*)(emb_u + (size_t)uid * 128);
#pragma unroll
        for (int it = 0; it < 4; ++it) {
            int u = it * 1024 + tid;       // 4096 float4 units
            int mm = u >> 5;
            int fq = u & 31;
            int t = time_seq[b * MM + mm];
            int tim = (t - 1) % HOURS + 1;
            int loc = full_seq[b * MM + mm];
            float4 a = ((const float4*)(emb_t + (size_t)tim * 128))[fq];
            float4 c = ((const float4*)(emb_loc + (size_t)loc * 128))[fq];
            float4 uu = Eu4[fq];
            uint2 pk;
            pk.x = pack2(a.x + c.x + uu.x, a.y + c.y + uu.y);
            pk.y = pack2(a.z + c.z + uu.z, a.w + c.w + uu.w);
            *(uint2*)&A_s[swz8(mm, fq >> 1) + (fq & 1) * 4] = pk;
        }
    }
    __syncthreads();

    // ---------------- phase 2: K, VT, Q GEMMs into LDS ----------------
    if (w < 8) {
        // K: n-row w.  D[n][m] -> k_lds[m][n], pack-4 along n(=e)
        bf16x8 af[4];
#pragma unroll
        for (int kf = 0; kf < 4; ++kf)
            af[kf] = load_w_frag(Wk + (size_t)(w * 16 + lr) * 128 + kf * 32 + lg * 8);
        f32x4 acc[8];
#pragma unroll
        for (int mt = 0; mt < 8; ++mt) acc[mt] = (f32x4){0.f, 0.f, 0.f, 0.f};
#pragma unroll
        for (int mt = 0; mt < 8; ++mt)
#pragma unroll
            for (int kf = 0; kf < 4; ++kf) {
                bf16x8 bf = *(const bf16x8*)&A_s[swz8(mt * 16 + lr, kf * 4 + lg)];
                acc[mt] = MFMA(af[kf], bf, acc[mt]);
            }
        int n0 = w * 16 + lg * 4;
#pragma unroll
        for (int mt = 0; mt < 8; ++mt) {
            int m = mt * 16 + lr;
            uint2 pk;
            pk.x = pack2(acc[mt][0], acc[mt][1]);
            pk.y = pack2(acc[mt][2], acc[mt][3]);
            *(uint2*)&B_s[swz8(m, n0 >> 3) + (n0 & 7)] = pk;
        }
    } else {
        // VT: A = J rows m (tile w8), B = Wv rows n.  D[m][n] -> vt_lds[e=n][m] scalar
        int w8 = w - 8;
        bf16x8 aj[4];
#pragma unroll
        for (int kf = 0; kf < 4; ++kf)
            aj[kf] = *(const bf16x8*)&A_s[swz8(w8 * 16 + lr, kf * 4 + lg)];
#pragma unroll
        for (int nt = 0; nt < 8; ++nt) {
            f32x4 acc = (f32x4){0.f, 0.f, 0.f, 0.f};
#pragma unroll
            for (int kf = 0; kf < 4; ++kf) {
                bf16x8 bw = load_w_frag(Wv + (size_t)(nt * 16 + lr) * 128 + kf * 32 + lg * 8);
                acc = MFMA(aj[kf], bw, acc);
            }
            // row = m = w8*16 + lg*4 + r (A row), col = n = nt*16 + lr (B row)
            int n = nt * 16 + lr;
#pragma unroll
            for (int r = 0; r < 4; ++r) {
                int m = w8 * 16 + lg * 4 + r;
                C_s[swz8(n, m >> 3) + (m & 7)] = (short)f2bfu(acc[r]);
            }
        }
    }
    // Q: 8 n-tiles x 4 m-tiles; wave w: n-tile (w&7), m-tiles {0,1} if w<8 else {2,3}
    {
        int nt = w & 7;
        int mtb = (w < 8) ? 0 : 2;
        bf16x8 aq[4];
#pragma unroll
        for (int kf = 0; kf < 4; ++kf)
            aq[kf] = load_w_frag(Wq + (size_t)(nt * 16 + lr) * 128 + kf * 32 + lg * 8);
#pragma unroll
        for (int mi = 0; mi < 2; ++mi) {
            int mt = mtb + mi;
            f32x4 acc = (f32x4){0.f, 0.f, 0.f, 0.f};
#pragma unroll
            for (int kf = 0; kf < 4; ++kf) {
                bf16x8 bf = *(const bf16x8*)&A_s[swz8(i0base + mt * 16 + lr, kf * 4 + lg)];
                acc = MFMA(aq[kf], bf, acc);
            }
            int iloc = mt * 16 + lr;
            int n0 = nt * 16 + lg * 4;
            uint2 pk;
            pk.x = pack2(acc[0], acc[1]);
            pk.y = pack2(acc[2], acc[3]);
            *(uint2*)&D_s[swz8(iloc, n0 >> 3) + (n0 & 7)] = pk;
        }
    }
    __syncthreads();

    // ---------------- phase 3a: QK^T -> S (f32, stride 132) ----------------
    float* Sf = (float*)A_s;
    {
        int chunk = w >> 2, sub = w & 3;
        bf16x8 qf[4];
#pragma unroll
        for (int kf = 0; kf < 4; ++kf)
            qf[kf] = *(const bf16x8*)&D_s[swz8(chunk * 16 + lr, kf * 4 + lg)];
#pragma unroll
        for (int t2 = 0; t2 < 2; ++t2) {
            int jt = sub * 2 + t2;
            f32x4 acc = (f32x4){0.f, 0.f, 0.f, 0.f};
#pragma unroll
            for (int kf = 0; kf < 4; ++kf) {
                bf16x8 bf = *(const bf16x8*)&B_s[swz8(jt * 16 + lr, kf * 4 + lg)];
                acc = MFMA(qf[kf], bf, acc);
            }
#pragma unroll
            for (int r = 0; r < 4; ++r)
                Sf[chunk * 2112 + (lg * 4 + r) * 132 + jt * 16 + lr] = acc[r];
        }
    }
    __syncthreads();

    // ---------------- phase 3b: softmax -> P (D region); tms/bsv ----------------
    {
        int chunk = tid >> 8, t256 = tid & 255;
        int r16 = t256 >> 4, u = t256 & 15, j0 = u * 8;
        int ig = i0base + chunk * 16 + r16;
        int mi = (ig < tl) ? 1 : 0;
        float c0_1 = coef[1] + coef[5];
        float c1_1 = (coef[3] - coef[1]) * 0.01f;
        float c2_1 = (coef[7] - coef[5]) * 0.01f;
        float c0_0 = coef[0] + coef[4];
        float c1_0 = (coef[2] - coef[0]) * 0.01f;
        float c2_0 = (coef[6] - coef[4]) * 0.01f;
        const float* sb = &Sf[chunk * 2112 + r16 * 132 + j0];
        float4 s01 = *(const float4*)sb;
        float4 s23 = *(const float4*)(sb + 4);
        float sv[8] = {s01.x, s01.y, s01.z, s01.w, s23.x, s23.y, s23.z, s23.w};
        const float4* m14 = (const float4*)(mat1 + ((size_t)(b * MM + ig) * MM + j0) * 2);
        float4 d0 = m14[0], d1 = m14[1], d2 = m14[2], d3 = m14[3];
        float ds[8] = {d0.x, d0.z, d1.x, d1.z, d2.x, d2.z, d3.x, d3.z};
        float dt[8] = {d0.y, d0.w, d1.y, d1.w, d2.y, d2.w, d3.y, d3.w};
        float lgv[8];
        int mk[8];
#pragma unroll
        for (int jj = 0; jj < 8; ++jj) {
            int j = j0 + jj;
            mk[jj] = mi & ((j < tl) ? 1 : 0);
            float cc0 = mk[jj] ? c0_1 : c0_0;
            float cc1 = mk[jj] ? c1_1 : c1_0;
            float cc2 = mk[jj] ? c2_1 : c2_0;
            lgv[jj] = sv[jj] + cc0 + cc1 * ds[jj] + cc2 * dt[jj];
        }
        float mx = lgv[0];
#pragma unroll
        for (int jj = 1; jj < 8; ++jj) mx = fmaxf(mx, lgv[jj]);
#pragma unroll
        for (int off = 8; off >= 1; off >>= 1) mx = fmaxf(mx, __shfl_xor(mx, off, 64));
        float ee[8], sum = 0.f;
#pragma unroll
        for (int jj = 0; jj < 8; ++jj) { ee[jj] = __expf(lgv[jj] - mx); sum += ee[jj]; }
#pragma unroll
        for (int off = 8; off >= 1; off >>= 1) sum += __shfl_xor(sum, off, 64);
        float inv = 1.0f / sum;
        uint4 pk;
        pk.x = pack2(ee[0] * inv * mk[0], ee[1] * inv * mk[1]);
        pk.y = pack2(ee[2] * inv * mk[2], ee[3] * inv * mk[3]);
        pk.z = pack2(ee[4] * inv * mk[4], ee[5] * inv * mk[5]);
        pk.w = pack2(ee[6] * inv * mk[6], ee[7] * inv * mk[7]);
        *(uint4*)&D_s[chunk * 2048 + swz8(r16, u)] = pk;
    }
    if (tid < 64) {
        int mg = i0base + tid;
        int vv = (mg < tl) ? 1 : 0;
        float ssl = vv ? coef[1] : coef[0];
        float ssu = vv ? coef[3] : coef[2];
        float stl = vv ? coef[5] : coef[4];
        float stu = vv ? coef[7] : coef[6];
        tms[tid] = ssl + stl + (stu - stl) * 0.01f * vecg[b * MM + mg];
        bsv[tid] = (ssu - ssl) * 0.01f;
    }
    __syncthreads();

    // ---------------- phase 3c: PV (waves 0-7) || stage cand + mat2 (waves 8-15) ----
    if (w < 8) {
        int chunk = w >> 1, eh = w & 1;
        bf16x8 bp[4];
#pragma unroll
        for (int kf = 0; kf < 4; ++kf)
            bp[kf] = *(const bf16x8*)&D_s[chunk * 2048 + swz8(lr, kf * 4 + lg)];
#pragma unroll
        for (int e4 = 0; e4 < 4; ++e4) {
            int et = eh * 4 + e4;
            f32x4 acc = (f32x4){0.f, 0.f, 0.f, 0.f};
#pragma unroll
            for (int kf = 0; kf < 4; ++kf) {
                bf16x8 af = *(const bf16x8*)&C_s[swz8(et * 16 + lr, kf * 4 + lg)];
                acc = MFMA(af, bp[kf], acc);
            }
            int iloc = chunk * 16 + lr;
            int e0 = et * 16 + lg * 4;
            uint2 pk;
            pk.x = pack2(acc[0], acc[1]);
            pk.y = pack2(acc[2], acc[3]);
            *(uint2*)&E_s[swz8(iloc, e0 >> 3) + (e0 & 7)] = pk;
        }
    } else {
        int w8 = w - 8;
        // cand rows w8*16 .. +16 into A region (bf16 swizzled)
#pragma unroll
        for (int it = 0; it < 8; ++it) {
            int u512 = it * 64 + l;
            int rr = u512 >> 5, fq = u512 & 31;
            int row = w8 * 16 + rr;
            int p = posneg[b * MM + row];
            float4 v = *(const float4*)(emb_loc + (size_t)p * 128 + fq * 4);
            uint2 pk;
            pk.x = pack2(v.x, v.y);
            pk.y = pack2(v.z, v.w);
            *(uint2*)&A_s[swz8(row, fq >> 1) + (fq & 1) * 4] = pk;
        }
        // mat2 own-half rows into B region (f32, stride 136)
        float* M2 = (float*)B_s;
#pragma unroll
        for (int it = 0; it < 4; ++it) {
            int idx = it * 64 + l;
            int mr = idx >> 5, fq = idx & 31;
            int mloc = w8 * 8 + mr;
            float4 v = *(const float4*)(mat2 + (size_t)(b * MM + i0base + mloc) * MM + fq * 4);
            *(float4*)&M2[mloc * 136 + fq * 4] = v;
        }
    }
    __syncthreads();

    // ---------------- phase 4: G = cand . sa^T, epilogue, atomicAdd ----------------
    {
        float* M2 = (float*)B_s;
        int lt = w >> 1;
        bf16x8 caf[4];
#pragma unroll
        for (int kf = 0; kf < 4; ++kf)
            caf[kf] = *(const bf16x8*)&A_s[swz8(lt * 16 + lr, kf * 4 + lg)];
        float vout[4] = {0.f, 0.f, 0.f, 0.f};
#pragma unroll
        for (int t2 = 0; t2 < 2; ++t2) {
            int mt = (w & 1) * 2 + t2;
            f32x4 acc = (f32x4){0.f, 0.f, 0.f, 0.f};
#pragma unroll
            for (int kf = 0; kf < 4; ++kf) {
                bf16x8 bf = *(const bf16x8*)&E_s[swz8(mt * 16 + lr, kf * 4 + lg)];
                acc = MFMA(caf[kf], bf, acc);
            }
            int mloc = mt * 16 + lr;
            float wt = tms[mloc], wb = bsv[mloc];
#pragma unroll
            for (int r = 0; r < 4; ++r) {
                int lidx = lt * 16 + lg * 4 + r;
                vout[r] += acc[r] * (wt + wb * M2[mloc * 136 + lidx]);
            }
        }
#pragma unroll
        for (int r = 0; r < 4; ++r) {
            float v = vout[r];
            v += __shfl_xor(v, 8, 64);
            v += __shfl_xor(v, 4, 64);
            v += __shfl_xor(v, 2, 64);
            v += __shfl_xor(v, 1, 64);
            if (lr == 0)
                atomicAdd(&outp[b * MM + lt * 16 + lg * 4 + r], v);
        }
    }
}

extern "C" void kernel_launch(void* const* d_in, const int* in_sizes, int n_in,
                              void* d_out, int out_size, void* d_ws, size_t ws_size,
                              hipStream_t stream) {
    const int* full_seq = (const int*)d_in[0];
    const int* time_seq = (const int*)d_in[1];
    const int* user     = (const int*)d_in[2];
    const int* posneg   = (const int*)d_in[3];
    const int* traj_len = (const int*)d_in[4];
    const float* mat1   = (const float*)d_in[5];
    const float* mat2   = (const float*)d_in[6];
    const float* vec    = (const float*)d_in[7];
    const float* emb_t  = (const float*)d_in[8];
    const float* emb_u  = (const float*)d_in[9];
    const float* emb_loc= (const float*)d_in[10];
    const float* emb_sl = (const float*)d_in[11];
    const float* emb_su = (const float*)d_in[12];
    const float* emb_tl = (const float*)d_in[13];
    const float* emb_tu = (const float*)d_in[14];
    const float* Wq     = (const float*)d_in[15];
    const float* Wk     = (const float*)d_in[16];
    const float* Wv     = (const float*)d_in[17];

    hipMemsetAsync(d_out, 0, (size_t)out_size * sizeof(float), stream);
    k_fused<<<64, 1024, 0, stream>>>(full_seq, time_seq, user, posneg, traj_len,
                                     mat1, mat2, vec, emb_t, emb_u, emb_loc,
                                     emb_sl, emb_su, emb_tl, emb_tu,
                                     Wq, Wk, Wv, (float*)d_out);
}

// Round 4
// 25.578 us; speedup vs baseline: 1.4521x; 1.4521x over previous
//
#include <hip/hip_runtime.h>
#include <hip/hip_bf16.h>

#define HOURS 24
#define NB 32
#define MM 128
#define EE 128

typedef short bf16x8 __attribute__((ext_vector_type(8)));
typedef float f32x4 __attribute__((ext_vector_type(4)));

__device__ __forceinline__ unsigned short f2bfu(float f) {
    __hip_bfloat16 h = __float2bfloat16(f);
    return __builtin_bit_cast(unsigned short, h);
}
__device__ __forceinline__ unsigned int pack2(float a, float b) {
    return (unsigned int)f2bfu(a) | ((unsigned int)f2bfu(b) << 16);
}
// swizzled short-index of 16B unit `unit` in row `row` of a [*][128] bf16 tile
__device__ __forceinline__ int swz8(int row, int unit) {
    return row * 128 + (((unit ^ (row & 7)) & 15) << 3);
}
// load 8 consecutive f32 from global, convert to bf16x8 fragment
__device__ __forceinline__ bf16x8 load_w_frag(const float* base) {
    float4 x = *(const float4*)base;
    float4 y = *(const float4*)(base + 4);
    union { unsigned int u[4]; bf16x8 v; } r;
    r.u[0] = pack2(x.x, x.y); r.u[1] = pack2(x.z, x.w);
    r.u[2] = pack2(y.x, y.y); r.u[3] = pack2(y.z, y.w);
    return r.v;
}

#define MFMA(a, b, c) __builtin_amdgcn_mfma_f32_16x16x32_bf16(a, b, c, 0, 0, 0)

// ---------------- Kernel 1: joint gather + Q/K/VT via MFMA (W frags direct from global)
// which<2: D = W (.) J^T  -> D[n][m], store q/k[m][n] (pack-4 contiguous along n)
// which=2: D = J (.) Wv^T -> D[m][n], store vt[n][m]  (pack-4 contiguous along m)
__global__ __launch_bounds__(256) void k_qkv(
    const int* __restrict__ time_seq, const int* __restrict__ full_seq,
    const int* __restrict__ user,
    const float* __restrict__ emb_t, const float* __restrict__ emb_u,
    const float* __restrict__ emb_loc,
    const float* __restrict__ Wq, const float* __restrict__ Wk, const float* __restrict__ Wv,
    short* __restrict__ qws, short* __restrict__ kws, short* __restrict__ vtws)
{
    __shared__ alignas(16) short Jl[64 * 128];   // 16KB
    int b = blockIdx.y;
    int which = blockIdx.x >> 1;
    int half = blockIdx.x & 1;
    int m0 = half * 64;
    int tid = threadIdx.x;
    int l = tid & 63, w = tid >> 6;
    int lr = l & 15, lg = l >> 4;

    // stage joint-half (gather-sum, f32 -> bf16, swizzled)
    int uid = user[b];
    const float4* Eu4 = (const float4*)(emb_u + (size_t)uid * 128);
#pragma unroll
    for (int it = 0; it < 8; ++it) {
        int i4 = it * 256 + tid;          // 2048 float4
        int mm = i4 >> 5;
        int fq = i4 & 31;
        int m = m0 + mm;
        int t = time_seq[b * MM + m];
        int tim = (t - 1) % HOURS + 1;
        int loc = full_seq[b * MM + m];
        float4 a = ((const float4*)(emb_t + (size_t)tim * 128))[fq];
        float4 c = ((const float4*)(emb_loc + (size_t)loc * 128))[fq];
        float4 u = Eu4[fq];
        uint2 pk;
        pk.x = pack2(a.x + c.x + u.x, a.y + c.y + u.y);
        pk.y = pack2(a.z + c.z + u.z, a.w + c.w + u.w);
        *(uint2*)&Jl[swz8(mm, fq >> 1) + (fq & 1) * 4] = pk;
    }
    __syncthreads();

    if (which < 2) {
        const float* W = which ? Wk : Wq;
        short* outp = which ? kws : qws;
        bf16x8 af[2][4];
#pragma unroll
        for (int nt = 0; nt < 2; ++nt) {
            int n = (2 * w + nt) * 16 + lr;
#pragma unroll
            for (int kf = 0; kf < 4; ++kf)
                af[nt][kf] = load_w_frag(W + (size_t)n * 128 + kf * 32 + lg * 8);
        }
        f32x4 acc[2][4];
#pragma unroll
        for (int nt = 0; nt < 2; ++nt)
#pragma unroll
            for (int mt = 0; mt < 4; ++mt) acc[nt][mt] = (f32x4){0.f, 0.f, 0.f, 0.f};
#pragma unroll
        for (int mt = 0; mt < 4; ++mt) {
            bf16x8 bf[4];
#pragma unroll
            for (int kf = 0; kf < 4; ++kf)
                bf[kf] = *(const bf16x8*)&Jl[swz8(mt * 16 + lr, kf * 4 + lg)];
#pragma unroll
            for (int nt = 0; nt < 2; ++nt)
#pragma unroll
                for (int kf = 0; kf < 4; ++kf)
                    acc[nt][mt] = MFMA(af[nt][kf], bf[kf], acc[nt][mt]);
        }
#pragma unroll
        for (int nt = 0; nt < 2; ++nt)
#pragma unroll
            for (int mt = 0; mt < 4; ++mt) {
                int mg = m0 + mt * 16 + lr;
                int n0 = (2 * w + nt) * 16 + lg * 4;
                uint2 pk;
                pk.x = pack2(acc[nt][mt][0], acc[nt][mt][1]);
                pk.y = pack2(acc[nt][mt][2], acc[nt][mt][3]);
                *(uint2*)&outp[(size_t)(b * MM + mg) * EE + n0] = pk;
            }
    } else {
        bf16x8 bfr[2][4];
#pragma unroll
        for (int nt = 0; nt < 2; ++nt) {
            int n = (2 * w + nt) * 16 + lr;
#pragma unroll
            for (int kf = 0; kf < 4; ++kf)
                bfr[nt][kf] = load_w_frag(Wv + (size_t)n * 128 + kf * 32 + lg * 8);
        }
        f32x4 acc[4][2];
#pragma unroll
        for (int mt = 0; mt < 4; ++mt)
#pragma unroll
            for (int nt = 0; nt < 2; ++nt) acc[mt][nt] = (f32x4){0.f, 0.f, 0.f, 0.f};
#pragma unroll
        for (int mt = 0; mt < 4; ++mt) {
            bf16x8 af[4];
#pragma unroll
            for (int kf = 0; kf < 4; ++kf)
                af[kf] = *(const bf16x8*)&Jl[swz8(mt * 16 + lr, kf * 4 + lg)];
#pragma unroll
            for (int nt = 0; nt < 2; ++nt)
#pragma unroll
                for (int kf = 0; kf < 4; ++kf)
                    acc[mt][nt] = MFMA(af[kf], bfr[nt][kf], acc[mt][nt]);
        }
#pragma unroll
        for (int mt = 0; mt < 4; ++mt)
#pragma unroll
            for (int nt = 0; nt < 2; ++nt) {
                int ng = (2 * w + nt) * 16 + lr;
                int mp = m0 + mt * 16 + lg * 4;
                uint2 pk;
                pk.x = pack2(acc[mt][nt][0], acc[mt][nt][1]);
                pk.y = pack2(acc[mt][nt][2], acc[mt][nt][3]);
                *(uint2*)&vtws[(size_t)(b * MM + ng) * MM + mp] = pk;
            }
    }
}

// ---------------- Kernel 2: attention; K/VT/Q fragments direct from global ----------
__global__ __launch_bounds__(256) void k_attn(
    const short* __restrict__ qws, const short* __restrict__ kws,
    const short* __restrict__ vtws,
    const float* __restrict__ mat1, const int* __restrict__ traj_len,
    const float* __restrict__ esl, const float* __restrict__ esu,
    const float* __restrict__ etl, const float* __restrict__ etu,
    short* __restrict__ saws)
{
    __shared__ alignas(16) float Sf[16 * 132];   // 8448B
    __shared__ alignas(16) short Pl[16 * 128];   // 4KB
    __shared__ float coef[8];

    int b = blockIdx.y;
    int i0 = blockIdx.x * 16;
    int tid = threadIdx.x;
    int l = tid & 63, w = tid >> 6;
    int lr = l & 15, lg = l >> 4;
    int tl = traj_len[b];

    // coefs: wave w computes table sums 2w, 2w+1
    {
        const float* tb[4] = {esl, esu, etl, etu};
#pragma unroll
        for (int s = 0; s < 2; ++s) {
            int c = 2 * w + s;
            const float* t = tb[c >> 1];
            float v = t[(c & 1) * 128 + l] + t[(c & 1) * 128 + 64 + l];
#pragma unroll
            for (int off = 32; off >= 1; off >>= 1) v += __shfl_xor(v, off, 64);
            if (l == 0) coef[c] = v;
        }
    }
    // Q A-frags direct from global
    bf16x8 qf[4];
#pragma unroll
    for (int kf = 0; kf < 4; ++kf)
        qf[kf] = *(const bf16x8*)&qws[(size_t)(b * MM + i0 + lr) * EE + kf * 32 + lg * 8];

    // QK^T: wave w covers j-tiles {2w, 2w+1}; K B-frags direct from global
#pragma unroll
    for (int t2 = 0; t2 < 2; ++t2) {
        int jt = 2 * w + t2;
        f32x4 acc = (f32x4){0.f, 0.f, 0.f, 0.f};
#pragma unroll
        for (int kf = 0; kf < 4; ++kf) {
            bf16x8 bf = *(const bf16x8*)&kws[(size_t)(b * MM + jt * 16 + lr) * EE + kf * 32 + lg * 8];
            acc = MFMA(qf[kf], bf, acc);
        }
#pragma unroll
        for (int r = 0; r < 4; ++r)
            Sf[(lg * 4 + r) * 132 + jt * 16 + lr] = acc[r];
    }
    __syncthreads();

    // softmax: thread = (row r16, 8-col chunk u)
    {
        int r16 = tid >> 4, u = tid & 15;
        int j0 = u * 8;
        int i = i0 + r16;
        int mi = (i < tl) ? 1 : 0;
        float c0_1 = coef[1] + coef[5];
        float c1_1 = (coef[3] - coef[1]) * 0.01f;
        float c2_1 = (coef[7] - coef[5]) * 0.01f;
        float c0_0 = coef[0] + coef[4];
        float c1_0 = (coef[2] - coef[0]) * 0.01f;
        float c2_0 = (coef[6] - coef[4]) * 0.01f;
        const float* sb = &Sf[r16 * 132 + j0];
        float4 s01 = *(const float4*)sb;
        float4 s23 = *(const float4*)(sb + 4);
        float sv[8] = {s01.x, s01.y, s01.z, s01.w, s23.x, s23.y, s23.z, s23.w};
        const float4* m14 = (const float4*)(mat1 + ((size_t)(b * MM + i) * MM + j0) * 2);
        float4 d0 = m14[0], d1 = m14[1], d2 = m14[2], d3 = m14[3];
        float ds[8] = {d0.x, d0.z, d1.x, d1.z, d2.x, d2.z, d3.x, d3.z};
        float dt[8] = {d0.y, d0.w, d1.y, d1.w, d2.y, d2.w, d3.y, d3.w};
        float lgv[8];
        int mk[8];
#pragma unroll
        for (int jj = 0; jj < 8; ++jj) {
            int j = j0 + jj;
            mk[jj] = mi & ((j < tl) ? 1 : 0);
            float cc0 = mk[jj] ? c0_1 : c0_0;
            float cc1 = mk[jj] ? c1_1 : c1_0;
            float cc2 = mk[jj] ? c2_1 : c2_0;
            lgv[jj] = sv[jj] + cc0 + cc1 * ds[jj] + cc2 * dt[jj];
        }
        float mx = lgv[0];
#pragma unroll
        for (int jj = 1; jj < 8; ++jj) mx = fmaxf(mx, lgv[jj]);
#pragma unroll
        for (int off = 8; off >= 1; off >>= 1) mx = fmaxf(mx, __shfl_xor(mx, off, 64));
        float ee[8], sum = 0.f;
#pragma unroll
        for (int jj = 0; jj < 8; ++jj) { ee[jj] = __expf(lgv[jj] - mx); sum += ee[jj]; }
#pragma unroll
        for (int off = 8; off >= 1; off >>= 1) sum += __shfl_xor(sum, off, 64);
        float inv = 1.0f / sum;
        uint4 pk;
        pk.x = pack2(ee[0] * inv * mk[0], ee[1] * inv * mk[1]);
        pk.y = pack2(ee[2] * inv * mk[2], ee[3] * inv * mk[3]);
        pk.z = pack2(ee[4] * inv * mk[4], ee[5] * inv * mk[5]);
        pk.w = pack2(ee[6] * inv * mk[6], ee[7] * inv * mk[7]);
        *(uint4*)&Pl[swz8(r16, u)] = pk;
    }
    __syncthreads();

    // PV: sa^T = VT (.) P^T ; VT A-frags direct from global; D[e][i] -> sa[i][e] pack-4
    bf16x8 bp[4];
#pragma unroll
    for (int kf = 0; kf < 4; ++kf)
        bp[kf] = *(const bf16x8*)&Pl[swz8(lr, kf * 4 + lg)];
#pragma unroll
    for (int t2 = 0; t2 < 2; ++t2) {
        int et = 2 * w + t2;
        f32x4 acc = (f32x4){0.f, 0.f, 0.f, 0.f};
#pragma unroll
        for (int kf = 0; kf < 4; ++kf) {
            bf16x8 af = *(const bf16x8*)&vtws[(size_t)(b * MM + et * 16 + lr) * MM + kf * 32 + lg * 8];
            acc = MFMA(af, bp[kf], acc);
        }
        int ig = i0 + lr;
        int e0 = et * 16 + lg * 4;
        uint2 pk;
        pk.x = pack2(acc[0], acc[1]);
        pk.y = pack2(acc[2], acc[3]);
        *(uint2*)&saws[(size_t)(b * MM + ig) * EE + e0] = pk;
    }
}

// ---------------- Kernel 3: G = cand (.) sa^T ; epilogue; 16 l per block ----------
__global__ __launch_bounds__(256) void k_final(
    const short* __restrict__ saws, const int* __restrict__ posneg,
    const float* __restrict__ emb_loc, const float* __restrict__ mat2,
    const float* __restrict__ vecg, const int* __restrict__ traj_len,
    const float* __restrict__ esl, const float* __restrict__ esu,
    const float* __restrict__ etl, const float* __restrict__ etu,
    float* __restrict__ outp)
{
    __shared__ float coef[8];
    __shared__ float tms[128], bsv[128];
    __shared__ float PART[4][16];

    int b = blockIdx.y;
    int l0 = blockIdx.x * 16;
    int tid = threadIdx.x;
    int l = tid & 63, w = tid >> 6;
    int lr = l & 15, lg = l >> 4;
    int tl = traj_len[b];

    {
        const float* tb[4] = {esl, esu, etl, etu};
#pragma unroll
        for (int s = 0; s < 2; ++s) {
            int c = 2 * w + s;
            const float* t = tb[c >> 1];
            float v = t[(c & 1) * 128 + l] + t[(c & 1) * 128 + 64 + l];
#pragma unroll
            for (int off = 32; off >= 1; off >>= 1) v += __shfl_xor(v, off, 64);
            if (l == 0) coef[c] = v;
        }
    }
    // cand A-frags direct from emb_loc via posneg (gather, no LDS)
    int p = posneg[b * MM + l0 + lr];
    bf16x8 caf[4];
#pragma unroll
    for (int kf = 0; kf < 4; ++kf)
        caf[kf] = load_w_frag(emb_loc + (size_t)p * 128 + kf * 32 + lg * 8);
    __syncthreads();

    if (tid < 128) {
        int vv = (tid < tl) ? 1 : 0;
        float ssl = vv ? coef[1] : coef[0];
        float ssu = vv ? coef[3] : coef[2];
        float stl = vv ? coef[5] : coef[4];
        float stu = vv ? coef[7] : coef[6];
        tms[tid] = ssl + stl + (stu - stl) * 0.01f * vecg[b * MM + tid];
        bsv[tid] = (ssu - ssl) * 0.01f;
    }
    __syncthreads();

    // G: wave w covers m-tiles {2w, 2w+1}; sa B-frags direct from global
    float vout[4] = {0.f, 0.f, 0.f, 0.f};
#pragma unroll
    for (int t2 = 0; t2 < 2; ++t2) {
        int mt = 2 * w + t2;
        f32x4 acc = (f32x4){0.f, 0.f, 0.f, 0.f};
#pragma unroll
        for (int kf = 0; kf < 4; ++kf) {
            bf16x8 bf = *(const bf16x8*)&saws[(size_t)(b * MM + mt * 16 + lr) * EE + kf * 32 + lg * 8];
            acc = MFMA(caf[kf], bf, acc);
        }
        int mloc = mt * 16 + lr;
        float wt = tms[mloc], wb = bsv[mloc];
        float4 m2 = *(const float4*)&mat2[(size_t)(b * MM + mloc) * MM + l0 + lg * 4];
        vout[0] += acc[0] * (wt + wb * m2.x);
        vout[1] += acc[1] * (wt + wb * m2.y);
        vout[2] += acc[2] * (wt + wb * m2.z);
        vout[3] += acc[3] * (wt + wb * m2.w);
    }
#pragma unroll
    for (int r = 0; r < 4; ++r) {
        float v = vout[r];
        v += __shfl_xor(v, 1, 64);
        v += __shfl_xor(v, 2, 64);
        v += __shfl_xor(v, 4, 64);
        v += __shfl_xor(v, 8, 64);
        if (lr == 0) PART[w][lg * 4 + r] = v;
    }
    __syncthreads();
    if (tid < 16)
        outp[b * MM + l0 + tid] = PART[0][tid] + PART[1][tid] + PART[2][tid] + PART[3][tid];
}

extern "C" void kernel_launch(void* const* d_in, const int* in_sizes, int n_in,
                              void* d_out, int out_size, void* d_ws, size_t ws_size,
                              hipStream_t stream) {
    const int* full_seq = (const int*)d_in[0];
    const int* time_seq = (const int*)d_in[1];
    const int* user     = (const int*)d_in[2];
    const int* posneg   = (const int*)d_in[3];
    const int* traj_len = (const int*)d_in[4];
    const float* mat1   = (const float*)d_in[5];
    const float* mat2   = (const float*)d_in[6];
    const float* vec    = (const float*)d_in[7];
    const float* emb_t  = (const float*)d_in[8];
    const float* emb_u  = (const float*)d_in[9];
    const float* emb_loc= (const float*)d_in[10];
    const float* emb_sl = (const float*)d_in[11];
    const float* emb_su = (const float*)d_in[12];
    const float* emb_tl = (const float*)d_in[13];
    const float* emb_tu = (const float*)d_in[14];
    const float* Wq     = (const float*)d_in[15];
    const float* Wk     = (const float*)d_in[16];
    const float* Wv     = (const float*)d_in[17];

    short* qws  = (short*)d_ws;
    short* kws  = qws + (size_t)NB * MM * EE;
    short* vtws = kws + (size_t)NB * MM * EE;
    short* saws = vtws + (size_t)NB * MM * EE;

    k_qkv<<<dim3(6, 32), 256, 0, stream>>>(time_seq, full_seq, user,
                                           emb_t, emb_u, emb_loc,
                                           Wq, Wk, Wv, qws, kws, vtws);
    k_attn<<<dim3(8, 32), 256, 0, stream>>>(qws, kws, vtws, mat1, traj_len,
                                            emb_sl, emb_su, emb_tl, emb_tu, saws);
    k_final<<<dim3(8, 32), 256, 0, stream>>>(saws, posneg, emb_loc, mat2, vec,
                                             traj_len, emb_sl, emb_su, emb_tl, emb_tu,
                                             (float*)d_out);
}